// Round 7
// baseline (366.032 us; speedup 1.0000x reference)
//
#include <hip/hip_runtime.h>
#include <hip/hip_bf16.h>

// B=16, N=2048, D=64 scaled-dot-product attention, fp32 in/out.
// Outputs concatenated: out [B,N,D] then attn_weights [B,N,N].
//
// R7 = R6 with kernel-B LDS-issue diet:
//  - attn written DIRECTLY from C-regs (R0-verified indexing; 64B/quad
//    segments, adjacent ns-stores merge to 128B lines in L2; nt dropped)
//  - P C->A transform via packed bf16 P^T (PsT): 4 ds_write_b64 + 8
//    ds_read_u16 per tile, replacing 16 b32 writes + 8 b128 reads
//  - PV accumulates UNNORMALIZED P; O scaled by invl at epilogue
#define B_  16
#define N_  2048
#define D_  64
// scale * log2(e) = (1/8) * 1.4426950408889634
#define SCALE_LOG2 0.18033688011112042f

typedef __attribute__((ext_vector_type(8))) short  frag8;   // 8 bf16 (4 VGPRs)
typedef __attribute__((ext_vector_type(4))) float  floatx4; // 4 fp32 acc

union FragU { frag8 fr; unsigned short us[8]; };

__device__ __forceinline__ unsigned short f2bf(float f) {
    // native cast: compiler packs pairs into v_cvt_pk_bf16_f32
    return __builtin_bit_cast(unsigned short, __float2bfloat16(f));
}
__device__ __forceinline__ float exp2fast(float x) {
    return __builtin_amdgcn_exp2f(x);   // args O(+-30), safe
}

// ======================= kernel A: denominators ==========================
// grid 2048 = 8 xcd * (2 b * 32 qtile * 4 kquarter). Each block: 64 Q rows
// x 512 keys, partial exp-sums -> atomicAdd ws[b][row].
__global__ __launch_bounds__(256) void denom_kernel(
    const float* __restrict__ Q, const float* __restrict__ K,
    float* __restrict__ ws)
{
    __shared__ unsigned short Ks[64][72];

    const int id    = blockIdx.x;
    const int xcd   = id & 7;
    const int s     = id >> 3;            // 0..255
    const int b     = xcd * 2 + (s >> 7); // xcd owns batches {2x, 2x+1}
    const int rem   = s & 127;
    const int qtile = rem >> 2;           // 0..31
    const int kq    = rem & 3;            // 0..3
    const int qbase = qtile * 64;
    const int kbase = kq * 512;
    const size_t bN = (size_t)b * N_;

    const int tid  = threadIdx.x;
    const int w    = tid >> 6;
    const int lane = tid & 63;
    const int lm   = lane & 15;
    const int quad = lane >> 4;
    const int q8   = quad * 8;
    const int srow = tid >> 2;
    const int sc0  = (tid & 3) * 16;

    // Q frags: wave-private rows, direct global->reg
    FragU aq0, aq1;
    {
        const float* qp = Q + (bN + qbase + w*16 + lm) * D_;
        float4 f0 = *(const float4*)(qp + q8);
        float4 f1 = *(const float4*)(qp + q8 + 4);
        float4 f2 = *(const float4*)(qp + 32 + q8);
        float4 f3 = *(const float4*)(qp + 36 + q8);
        #pragma unroll
        for (int j = 0; j < 4; ++j) {
            aq0.us[j]   = f2bf(f0[j]);  aq0.us[4+j] = f2bf(f1[j]);
            aq1.us[j]   = f2bf(f2[j]);  aq1.us[4+j] = f2bf(f3[j]);
        }
    }

    float s4[4] = {0.f, 0.f, 0.f, 0.f};

    ushort4 kreg[4];
    {
        const float4* src = (const float4*)(K + (bN + kbase + srow) * D_ + sc0);
        #pragma unroll
        for (int i = 0; i < 4; ++i) {
            float4 f = src[i];
            kreg[i].x=f2bf(f.x); kreg[i].y=f2bf(f.y);
            kreg[i].z=f2bf(f.z); kreg[i].w=f2bf(f.w);
        }
    }

    for (int t = 0; t < 8; ++t) {          // 8 tiles x 64 keys = 512
        __syncthreads();
        #pragma unroll
        for (int i = 0; i < 4; ++i)
            *(ushort4*)&Ks[srow][sc0 + i*4] = kreg[i];
        __syncthreads();

        float4 fnext[4];
        if (t + 1 < 8) {
            const float4* src = (const float4*)(K + (bN + kbase + (t+1)*64 + srow) * D_ + sc0);
            #pragma unroll
            for (int i = 0; i < 4; ++i) fnext[i] = src[i];
        }

        __builtin_amdgcn_s_setprio(1);
        #pragma unroll
        for (int ns = 0; ns < 4; ++ns) {
            frag8 b0 = *(const frag8*)&Ks[ns*16 + lm][q8];
            frag8 b1 = *(const frag8*)&Ks[ns*16 + lm][32 + q8];
            floatx4 a = {0.f, 0.f, 0.f, 0.f};
            a = __builtin_amdgcn_mfma_f32_16x16x32_bf16(aq0.fr, b0, a, 0, 0, 0);
            a = __builtin_amdgcn_mfma_f32_16x16x32_bf16(aq1.fr, b1, a, 0, 0, 0);
            #pragma unroll
            for (int r = 0; r < 4; ++r)
                s4[r] += exp2fast(a[r] * SCALE_LOG2);
        }
        __builtin_amdgcn_s_setprio(0);

        if (t + 1 < 8) {
            #pragma unroll
            for (int i = 0; i < 4; ++i) {
                kreg[i].x=f2bf(fnext[i].x); kreg[i].y=f2bf(fnext[i].y);
                kreg[i].z=f2bf(fnext[i].z); kreg[i].w=f2bf(fnext[i].w);
            }
        }
    }

    // reduce over the 16 lm lanes, then one atomic per (quad,row)
    #pragma unroll
    for (int r = 0; r < 4; ++r) {
        float v = s4[r];
        #pragma unroll
        for (int off = 1; off < 16; off <<= 1)
            v += __shfl_xor(v, off, 64);
        if (lm == 0)
            atomicAdd(&ws[bN + qbase + w*16 + quad*4 + r], v);
    }
}

// ======================= kernel B: attn + O ==============================
// grid 1024 = 8 xcd * (2 b * 32 qtile * 2 khalf). Each block: 64 Q rows x
// 1024 keys (16 tiles). LDS 28.7KB, 4 blocks/CU.
struct __align__(16) SMemB {
    unsigned short Ks[64][72];     // K tile bf16
    unsigned short Vt[64][72];     // V^T tile bf16 [dim][key ^ swz]
    unsigned short PsT[4][64][20]; // per-wave P^T bf16 [key][q], stride-20 pad
};

__global__ __launch_bounds__(256, 4) void attn_kernel(
    const float* __restrict__ Q, const float* __restrict__ K,
    const float* __restrict__ V, const float* __restrict__ ws,
    float* __restrict__ out, float* __restrict__ attn)
{
    __shared__ SMemB sm;

    const int id    = blockIdx.x;
    const int xcd   = id & 7;
    const int s     = id >> 3;            // 0..127
    const int b     = xcd * 2 + (s >> 6);
    const int rem   = s & 63;
    const int qtile = rem >> 1;           // 0..31
    const int kh    = rem & 1;            // key half
    const int qbase = qtile * 64;
    const int kbase = kh * 1024;
    const size_t bN = (size_t)b * N_;

    const int tid  = threadIdx.x;
    const int w    = tid >> 6;
    const int lane = tid & 63;
    const int lm   = lane & 15;
    const int quad = lane >> 4;
    const int q8   = quad * 8;
    const int srow = tid >> 2;
    const int sc0  = (tid & 3) * 16;
    const int vswz = srow ^ (((sc0 >> 4) & 3) << 3);   // Vt bank swizzle

    // Q frags
    FragU aq0, aq1;
    {
        const float* qp = Q + (bN + qbase + w*16 + lm) * D_;
        float4 f0 = *(const float4*)(qp + q8);
        float4 f1 = *(const float4*)(qp + q8 + 4);
        float4 f2 = *(const float4*)(qp + 32 + q8);
        float4 f3 = *(const float4*)(qp + 36 + q8);
        #pragma unroll
        for (int j = 0; j < 4; ++j) {
            aq0.us[j]   = f2bf(f0[j]);  aq0.us[4+j] = f2bf(f1[j]);
            aq1.us[j]   = f2bf(f2[j]);  aq1.us[4+j] = f2bf(f3[j]);
        }
    }

    // denominators (complete: kernel A finished before we launched)
    float invl[4];
    #pragma unroll
    for (int r = 0; r < 4; ++r)
        invl[r] = 1.0f / ws[bN + qbase + w*16 + quad*4 + r];

    floatx4 oacc[4];
    #pragma unroll
    for (int dg = 0; dg < 4; ++dg) oacc[dg] = (floatx4){0.f, 0.f, 0.f, 0.f};

    float4 fk[4], fv[4];
    auto loadS = [&](int t) {
        const float4* srcK = (const float4*)(K + (bN + kbase + t*64 + srow) * D_ + sc0);
        const float4* srcV = (const float4*)(V + (bN + kbase + t*64 + srow) * D_ + sc0);
        #pragma unroll
        for (int i = 0; i < 4; ++i) fk[i] = srcK[i];
        #pragma unroll
        for (int i = 0; i < 4; ++i) fv[i] = srcV[i];
    };

    loadS(0);
    for (int t = 0; t < 16; ++t) {
        __syncthreads();   // previous tile consumed
        #pragma unroll
        for (int i = 0; i < 4; ++i) {
            ushort4 u; u.x=f2bf(fk[i].x); u.y=f2bf(fk[i].y);
                       u.z=f2bf(fk[i].z); u.w=f2bf(fk[i].w);
            *(ushort4*)&sm.Ks[srow][sc0 + i*4] = u;
        }
        #pragma unroll
        for (int i = 0; i < 4; ++i) {   // V transposed: Vt[dim][key^swz]
            sm.Vt[sc0 + i*4 + 0][vswz] = f2bf(fv[i].x);
            sm.Vt[sc0 + i*4 + 1][vswz] = f2bf(fv[i].y);
            sm.Vt[sc0 + i*4 + 2][vswz] = f2bf(fv[i].z);
            sm.Vt[sc0 + i*4 + 3][vswz] = f2bf(fv[i].w);
        }
        __syncthreads();   // tile t visible

        if (t + 1 < 16) loadS(t + 1);   // in flight under compute

        // QK^T
        floatx4 acc[4];
        __builtin_amdgcn_s_setprio(1);
        #pragma unroll
        for (int ns = 0; ns < 4; ++ns) {
            frag8 b0 = *(const frag8*)&sm.Ks[ns*16 + lm][q8];
            frag8 b1 = *(const frag8*)&sm.Ks[ns*16 + lm][32 + q8];
            floatx4 a = {0.f, 0.f, 0.f, 0.f};
            a = __builtin_amdgcn_mfma_f32_16x16x32_bf16(aq0.fr, b0, a, 0, 0, 0);
            a = __builtin_amdgcn_mfma_f32_16x16x32_bf16(aq1.fr, b1, a, 0, 0, 0);
            acc[ns] = a;
        }
        __builtin_amdgcn_s_setprio(0);

        // per ns: unnormalized exp -> PsT (packed bf16 P^T, b64 write);
        // normalized fp32 -> attn DIRECTLY from C-regs (64B/quad segments,
        // adjacent ns-stores merge to 128B lines in L2)
        #pragma unroll
        for (int ns = 0; ns < 4; ++ns) {
            float pu[4];
            #pragma unroll
            for (int r = 0; r < 4; ++r)
                pu[r] = exp2fast(acc[ns][r] * SCALE_LOG2);
            unsigned int w0 = (unsigned int)f2bf(pu[0]) | ((unsigned int)f2bf(pu[1]) << 16);
            unsigned int w1 = (unsigned int)f2bf(pu[2]) | ((unsigned int)f2bf(pu[3]) << 16);
            *(uint2*)&sm.PsT[w][ns*16 + lm][quad*4] = make_uint2(w0, w1);
            #pragma unroll
            for (int r = 0; r < 4; ++r)
                attn[(bN + qbase + w*16 + quad*4 + r) * N_
                     + kbase + t*64 + ns*16 + lm] = pu[r] * invl[r];
        }

        // P A-frags from PsT (unnormalized bf16): 8+8 ds_read_u16, ~2-way
        FragU pa0, pa1;
        #pragma unroll
        for (int j = 0; j < 8; ++j) {
            pa0.us[j] = sm.PsT[w][q8 + j][lm];
            pa1.us[j] = sm.PsT[w][32 + q8 + j][lm];
        }

        // PV accumulate, unnormalized (Vt read un-swizzles: q8 ^ (dg<<3))
        __builtin_amdgcn_s_setprio(1);
        #pragma unroll
        for (int dg = 0; dg < 4; ++dg) {
            const int kb = q8 ^ (dg << 3);
            frag8 v0 = *(const frag8*)&sm.Vt[dg*16 + lm][kb];
            frag8 v1 = *(const frag8*)&sm.Vt[dg*16 + lm][32 + kb];
            oacc[dg] = __builtin_amdgcn_mfma_f32_16x16x32_bf16(pa0.fr, v0, oacc[dg], 0, 0, 0);
            oacc[dg] = __builtin_amdgcn_mfma_f32_16x16x32_bf16(pa1.fr, v1, oacc[dg], 0, 0, 0);
        }
        __builtin_amdgcn_s_setprio(0);
    }

    // partial O -> global, normalized here (out zeroed; two khalf blocks add)
    #pragma unroll
    for (int dg = 0; dg < 4; ++dg)
        #pragma unroll
        for (int r = 0; r < 4; ++r)
            atomicAdd(&out[(bN + qbase + w*16 + quad*4 + r) * D_ + dg*16 + lm],
                      oacc[dg][r] * invl[r]);
}

extern "C" void kernel_launch(void* const* d_in, const int* in_sizes, int n_in,
                              void* d_out, int out_size, void* d_ws, size_t ws_size,
                              hipStream_t stream) {
    const float* Q = (const float*)d_in[0];
    const float* K = (const float*)d_in[1];
    const float* V = (const float*)d_in[2];
    float* out  = (float*)d_out;
    float* attn = out + (size_t)B_ * N_ * D_;   // tuple order: out, attn_weights
    float* ws   = (float*)d_ws;                 // denominators [B][N] (131 KB)

    hipMemsetAsync(ws, 0, (size_t)B_ * N_ * sizeof(float), stream);
    hipMemsetAsync(out, 0, (size_t)B_ * N_ * D_ * sizeof(float), stream);
    denom_kernel<<<dim3(2048), 256, 0, stream>>>(Q, K, ws);
    attn_kernel <<<dim3(1024), 256, 0, stream>>>(Q, K, V, ws, out, attn);
}